// Round 9
// baseline (179.288 us; speedup 1.0000x reference)
//
#include <hip/hip_runtime.h>
#include <stdint.h>

#define EPS 1e-8f

constexpr int HW = 16384;   // pixels per image (M and N dims)
constexpr int BM = 128;     // block M tile
constexpr int NG = 2048;    // n-group width per block (32 q-substeps of 64)

typedef __attribute__((ext_vector_type(4))) float floatx4;
typedef __attribute__((ext_vector_type(4))) int   intx4;
typedef __attribute__((ext_vector_type(8))) int   intx8;    // 32B = one f8f6f4 K=128 operand
typedef unsigned char u8;
typedef unsigned int u32;
typedef unsigned long long u64;

// Address-space-qualified pointers for global_load_lds (hipcc does NOT
// implicitly convert generic pointers to AS(1)/AS(3) builtin params).
typedef const __attribute__((address_space(1))) u32 gas_u32;
typedef __attribute__((address_space(3))) u32 las_u32;
__device__ inline void stage16(const void* g, void* l) {
    __builtin_amdgcn_global_load_lds((gas_u32*)g, (las_u32*)l, 16, 0, 0);
}

// HW packed fp8 e4m3 convert: 4 floats -> 4 bytes (2x v_cvt_pk_fp8_f32)
__device__ inline u32 pk4(float x0, float x1, float x2, float x3) {
    int t = __builtin_amdgcn_cvt_pk_fp8_f32(x0, x1, 0, false);
    t = __builtin_amdgcn_cvt_pk_fp8_f32(x2, x3, t, true);
    return (u32)t;
}

// ---------------------------------------------------------------------------
// Fragment layout (split-half, ds_read-conflict-free): pixel p, channel c:
//   g = p>>4 (16-px slab), r = p&15, kb = c>>7, q = (c>>5)&3, h = (c>>4)&1,
//   e8 = c&15;  byte = g*4096 + kb*2048 + h*1024 + (q*16+r)*16 + e8
// A 64-col slice (4 slabs) is 16KB CONTIGUOUS -> linear global_load_lds.
//
// PREP — SINGLE PASS (R8 post-mortem: every variant that re-reads a/b for
// conversion costs ~50+us regardless of cache state; so b is now stored RAW
// fp8 — same as a — and normalization moves to the gemm argmax epilogue
// via invb[col]. One streaming read of a+b total, sumsq accumulated in
// registers alongside the fp8 pack/store.)
// 512 blocks x 256 thr: block = 32 pixels x 256 channels.
// Thread (px = tid&31, wg = tid>>5) covers pixel p0+px, channels wg*32..+31.
// Wave load = 2 contiguous 128B segments. Also zeroes packed/out.
__global__ __launch_bounds__(256) void prep_kernel(const float* __restrict__ a,
                                                   const float* __restrict__ b,
                                                   float* __restrict__ sumsq_a,
                                                   float* __restrict__ sumsq_b,
                                                   u8* __restrict__ aF, u8* __restrict__ bF,
                                                   u64* __restrict__ packed,
                                                   float* __restrict__ out) {
    __shared__ float redb[8][33];
    __shared__ float reda[8][33];
    const int tid = threadIdx.x;
    const int px = tid & 31, wg = tid >> 5;      // 8 channel-groups x 32 channels
    const int p0 = blockIdx.x * 32;
    const int p = p0 + px;
    const int c0 = wg * 32;

    if (blockIdx.x < 64) packed[(size_t)blockIdx.x * 256 + tid] = 0ull;
    if (blockIdx.x == 0 && tid == 0) *out = 0.f;

    const u32 slab = ((u32)(p >> 4)) << 12;
    const u32 r16 = (u32)(p & 15) * 16;

    float sb = 0.f, sa = 0.f;
    #pragma unroll
    for (int k = 0; k < 8; ++k) {
        const int c = c0 + k * 4;
        const u32 fo = (u32)((c >> 7) * 2048 + ((c >> 4) & 1) * 1024 + (c & 15))
                     + (u32)(((c >> 5) & 3) * 256) + r16;   // fb + q*256 + (p&15)*16
        float x0 = b[(size_t)(c + 0) * HW + p], x1 = b[(size_t)(c + 1) * HW + p];
        float x2 = b[(size_t)(c + 2) * HW + p], x3 = b[(size_t)(c + 3) * HW + p];
        sb += x0 * x0 + x1 * x1 + x2 * x2 + x3 * x3;
        *(u32*)(bF + slab + fo) = pk4(x0, x1, x2, x3);      // RAW (no normalize)
        float y0 = a[(size_t)(c + 0) * HW + p], y1 = a[(size_t)(c + 1) * HW + p];
        float y2 = a[(size_t)(c + 2) * HW + p], y3 = a[(size_t)(c + 3) * HW + p];
        sa += y0 * y0 + y1 * y1 + y2 * y2 + y3 * y3;
        *(u32*)(aF + slab + fo) = pk4(y0, y1, y2, y3);
    }
    redb[wg][px] = sb; reda[wg][px] = sa;
    __syncthreads();
    if (tid < 32) {
        float B = 0.f, A = 0.f;
        #pragma unroll
        for (int j = 0; j < 8; ++j) { B += redb[j][tid]; A += reda[j][tid]; }
        sumsq_b[p0 + tid] = B;
        sumsq_a[p0 + tid] = A;
    }
}

// ---------------------------------------------------------------------------
// G: fused GEMM + argmax, MX-scaled fp8 (unit scales). R4/R8-verified
// structure (simple 2-buffer __syncthreads schedule, wave tile 64x32,
// 3 blocks/CU; R5-R7: every deeper-pipeline rewrite spilled). Deltas for
// raw-b: (1) invb for the 2048-col ng panel cached in 8KB LDS (40KB total,
// still 3 blocks/CU); (2) MFMA C = 0 (the +64 bias would scale by invb per
// column and corrupt the compare); (3) argmax compares v = acc*invb[col];
// (4) final pack uses the R0-verified sign-monotone map (v can be negative).
__global__ __launch_bounds__(256, 3) void gemm_argmax(const u8* __restrict__ aF,
                                                      const u8* __restrict__ bF,
                                                      const float* __restrict__ sumsq_b,
                                                      u64* __restrict__ packed) {
    __shared__ u8 sB[2][16384];
    __shared__ float invb_lds[2048];
    const int tid = threadIdx.x;
    const int w = tid >> 6, lane = tid & 63;
    const int q4 = lane >> 4, r15 = lane & 15;
    const int wm = w >> 1, wn = w & 1;

    const u32 bid = blockIdx.x;
    const u32 ng = bid & 7;          // n-group -> XCD (L2-resident B panel)
    const u32 mt = bid >> 3;         // 0..127 M tile
    const int p0 = (int)mt * BM;

    // A fragments resident: slab g = mt*8 + wm*4 + mi; two 16B halves at
    // g*4096 + kb*2048 + {0,1024} + lane*16
    const u8* gA = aF + (((size_t)(mt * 8 + wm * 4)) << 12) + (u32)lane * 16;
    intx8 Afr[4][2];
    #pragma unroll
    for (int mi = 0; mi < 4; ++mi)
        #pragma unroll
        for (int kb = 0; kb < 2; ++kb)
            Afr[mi][kb] = __builtin_shufflevector(
                *(const intx4*)(gA + (u32)(mi * 4096 + kb * 2048)),
                *(const intx4*)(gA + (u32)(mi * 4096 + kb * 2048 + 1024)),
                0, 1, 2, 3, 4, 5, 6, 7);

    // invb table for this panel (8 values/thread)
    #pragma unroll
    for (int i = 0; i < 8; ++i) {
        int idx = tid + i * 256;
        float B = sumsq_b[ng * 2048 + idx];
        invb_lds[idx] = 1.0f / (sqrtf(B + EPS) + EPS);
    }

    // B panel for this ng: qt slice = gQ + qt*16384, 16KB contiguous
    const u8* gQ = bF + ((size_t)ng << 19);
    const u32 so = (u32)w * 4096u + (u32)lane * 16u;    // stage src offset (per-lane)

    // prologue: stage qt=0 into buffer 0
    #pragma unroll
    for (int i = 0; i < 4; ++i)
        stage16(gQ + so + (u32)(i * 1024), &sB[0][w * 4096 + i * 1024]);

    float bestv[4][4];
    u32   bestq[4][4];
    #pragma unroll
    for (int mi = 0; mi < 4; ++mi)
        #pragma unroll
        for (int r = 0; r < 4; ++r) { bestv[mi][r] = -3.4e38f; bestq[mi][r] = 0; }

    u32 q0 = ng * 2048 + wn * 32 + (u32)r15;   // running col id (ni0); ni1 = +16
    const floatx4 Z = {0.f, 0.f, 0.f, 0.f};
    const int SCL = 0x7F7F7F7F;      // E8M0 127 = 2^0 -> unit scale

    __syncthreads();                 // buf0 + invb table ready

    int x = 0;
    for (int qt = 0; qt < 32; ++qt) {
        // stage qt+1 into the other buffer (loads span the whole compute phase)
        if (qt < 31) {
            const u8* gs = gQ + (u32)(qt + 1) * 16384u + so;
            u8* ls = &sB[x ^ 1][w * 4096];
            #pragma unroll
            for (int i = 0; i < 4; ++i)
                stage16(gs + (u32)(i * 1024), ls + i * 1024);
        }

        const u8* Lb = &sB[x][(u32)(wn * 2) * 4096u + (u32)lane * 16u];
        floatx4 acc[4][2];
        intx8 B0, B1;

        // kb = 0 (C = 0)
        { intx4 lo = *(const intx4*)(Lb);
          intx4 hi = *(const intx4*)(Lb + 1024);
          B0 = __builtin_shufflevector(lo, hi, 0, 1, 2, 3, 4, 5, 6, 7); }
        { intx4 lo = *(const intx4*)(Lb + 4096);
          intx4 hi = *(const intx4*)(Lb + 4096 + 1024);
          B1 = __builtin_shufflevector(lo, hi, 0, 1, 2, 3, 4, 5, 6, 7); }
        __builtin_amdgcn_s_setprio(1);
        #pragma unroll
        for (int mi = 0; mi < 4; ++mi)
            acc[mi][0] = __builtin_amdgcn_mfma_scale_f32_16x16x128_f8f6f4(
                Afr[mi][0], B0, Z, 0, 0, 0, SCL, 0, SCL);
        #pragma unroll
        for (int mi = 0; mi < 4; ++mi)
            acc[mi][1] = __builtin_amdgcn_mfma_scale_f32_16x16x128_f8f6f4(
                Afr[mi][0], B1, Z, 0, 0, 0, SCL, 0, SCL);
        __builtin_amdgcn_s_setprio(0);

        // kb = 1 (accumulate)
        { intx4 lo = *(const intx4*)(Lb + 2048);
          intx4 hi = *(const intx4*)(Lb + 2048 + 1024);
          B0 = __builtin_shufflevector(lo, hi, 0, 1, 2, 3, 4, 5, 6, 7); }
        { intx4 lo = *(const intx4*)(Lb + 4096 + 2048);
          intx4 hi = *(const intx4*)(Lb + 4096 + 2048 + 1024);
          B1 = __builtin_shufflevector(lo, hi, 0, 1, 2, 3, 4, 5, 6, 7); }
        __builtin_amdgcn_s_setprio(1);
        #pragma unroll
        for (int mi = 0; mi < 4; ++mi)
            acc[mi][0] = __builtin_amdgcn_mfma_scale_f32_16x16x128_f8f6f4(
                Afr[mi][1], B0, acc[mi][0], 0, 0, 0, SCL, 0, SCL);
        #pragma unroll
        for (int mi = 0; mi < 4; ++mi)
            acc[mi][1] = __builtin_amdgcn_mfma_scale_f32_16x16x128_f8f6f4(
                Afr[mi][1], B1, acc[mi][1], 0, 0, 0, SCL, 0, SCL);
        __builtin_amdgcn_s_setprio(0);

        // running argmax on v = acc * invb[col] (ascending scan keeps first)
        const u32 pc = (u32)qt * 64u + (u32)(wn * 32) + (u32)r15;
        const float inv0 = invb_lds[pc];
        const float inv1 = invb_lds[pc + 16];
        #pragma unroll
        for (int mi = 0; mi < 4; ++mi)
            #pragma unroll
            for (int r = 0; r < 4; ++r) {
                float v = acc[mi][0][r] * inv0;
                bool gt = v > bestv[mi][r];
                bestv[mi][r] = gt ? v : bestv[mi][r];
                bestq[mi][r] = gt ? q0 : bestq[mi][r];
            }
        #pragma unroll
        for (int mi = 0; mi < 4; ++mi)
            #pragma unroll
            for (int r = 0; r < 4; ++r) {
                float v = acc[mi][1][r] * inv1;
                bool gt = v > bestv[mi][r];
                bestv[mi][r] = gt ? v : bestv[mi][r];
                bestq[mi][r] = gt ? (q0 + 16u) : bestq[mi][r];
            }
        q0 += 64u;

        __syncthreads();             // staged buffer landed; all reads of sB[x] done
        x ^= 1;
    }

    // final: sign-monotone map (v may be negative), pack with ~q,
    // shuffle-reduce over r15 (stays in q4 group), 1 atomic/row/wave
    #pragma unroll
    for (int mi = 0; mi < 4; ++mi)
        #pragma unroll
        for (int r = 0; r < 4; ++r) {
            u32 m = __float_as_uint(bestv[mi][r]);
            m = m ^ (u32)(((int)m >> 31) | 0x80000000u);
            u64 pk = ((u64)m << 32) | (u64)(0xFFFFFFFFu - bestq[mi][r]);
            #pragma unroll
            for (int d = 1; d < 16; d <<= 1) {
                u64 o = __shfl_xor((unsigned long long)pk, d);
                pk = o > pk ? o : pk;
            }
            if (r15 == 0)
                atomicMax(&packed[p0 + wm * 64 + mi * 16 + q4 * 4 + r], pk);
        }
}

// ---------------------------------------------------------------------------
// L: loss from the argmax's own similarity value (no gather).
// Decode (R0-verified inverse monotone map): s = dot_raw/(sqrt(B+EPS)+EPS),
// so dot = s*(sqrt(B+EPS)+EPS) reconstructs the raw dot exactly.
__global__ void loss_kernel(const u64* __restrict__ packed,
                            const float* __restrict__ sumsq_a, const float* __restrict__ sumsq_b,
                            float* __restrict__ out) {
    int p = blockIdx.x * 256 + threadIdx.x;
    u64 pk = packed[p];
    u32 m = (u32)(pk >> 32);
    u32 u = (m & 0x80000000u) ? (m ^ 0x80000000u) : ~m;   // inverse monotone map
    float s = __uint_as_float(u);
    u32 q = 0xFFFFFFFFu - (u32)(pk & 0xFFFFFFFFull);
    float A = sumsq_a[p], B = sumsq_b[q];
    float dot = s * (sqrtf(B + EPS) + EPS);
    float cossim = dot / ((sqrtf(A) + EPS) * (sqrtf(B) + EPS));
    float v = (1.0f - cossim) * (1.0f / (float)HW);
    #pragma unroll
    for (int d = 1; d < 64; d <<= 1) v += __shfl_xor(v, d);
    if ((threadIdx.x & 63) == 0) atomicAdd(out, v);
}

// ---------------------------------------------------------------------------
extern "C" void kernel_launch(void* const* d_in, const int* in_sizes, int n_in,
                              void* d_out, int out_size, void* d_ws, size_t ws_size,
                              hipStream_t stream) {
    const float* a = (const float*)d_in[0];
    const float* b = (const float*)d_in[1];
    float* out = (float*)d_out;
    char* ws = (char*)d_ws;

    u8*    aF      = (u8*)ws;                                    // 4 MB
    u8*    bF      = (u8*)(ws + (size_t)4 * 1024 * 1024);        // 4 MB
    float* sumsq_a = (float*)(ws + (size_t)8 * 1024 * 1024);     // 64 KB
    float* sumsq_b = sumsq_a + HW;
    u64*   packed  = (u64*)(sumsq_b + HW);                       // 128 KB

    prep_kernel<<<dim3(HW / 32), 256, 0, stream>>>(a, b, sumsq_a, sumsq_b, aF, bF, packed, out);
    gemm_argmax<<<dim3((HW / BM) * (HW / NG)), 256, 0, stream>>>(aF, bF, sumsq_b, packed);
    loss_kernel<<<dim3(HW / 256), 256, 0, stream>>>(packed, sumsq_a, sumsq_b, out);
}

// Round 11
// 141.414 us; speedup vs baseline: 1.2678x; 1.2678x over previous
//
#include <hip/hip_runtime.h>
#include <stdint.h>

#define EPS 1e-8f

constexpr int HW = 16384;   // pixels per image (M and N dims)
constexpr int BM = 128;     // block M tile
constexpr int NG = 2048;    // n-group width per block (32 q-substeps of 64)

typedef __attribute__((ext_vector_type(4))) float floatx4;
typedef __attribute__((ext_vector_type(4))) int   intx4;
typedef __attribute__((ext_vector_type(8))) int   intx8;    // 32B = one f8f6f4 K=128 operand
typedef unsigned char u8;
typedef unsigned int u32;
typedef unsigned long long u64;

// Address-space-qualified pointers for global_load_lds (hipcc does NOT
// implicitly convert generic pointers to AS(1)/AS(3) builtin params).
typedef const __attribute__((address_space(1))) u32 gas_u32;
typedef __attribute__((address_space(3))) u32 las_u32;
__device__ inline void stage16(const void* g, void* l) {
    __builtin_amdgcn_global_load_lds((gas_u32*)g, (las_u32*)l, 16, 0, 0);
}

// HW packed fp8 e4m3 convert: 4 floats -> 4 bytes (2x v_cvt_pk_fp8_f32)
__device__ inline u32 pk4(float x0, float x1, float x2, float x3) {
    int t = __builtin_amdgcn_cvt_pk_fp8_f32(x0, x1, 0, false);
    t = __builtin_amdgcn_cvt_pk_fp8_f32(x2, x3, t, true);
    return (u32)t;
}

// ---------------------------------------------------------------------------
// Fragment layout (split-half, ds_read-conflict-free): pixel p, channel c:
//   g = p>>4 (16-px slab), r = p&15, kb = c>>7, q = (c>>5)&3, h = (c>>4)&1,
//   e8 = c&15;  byte = g*4096 + kb*2048 + h*1024 + (q*16+r)*16 + e8
// A 64-col slice (4 slabs) is 16KB CONTIGUOUS -> linear global_load_lds.
//
// PREP — DENSE-STORE single read (R9 post-mortem: every slow prep variant
// shared u32-at-16B-stride fragment stores = 4B per 16B span -> L2
// write-allocate + HBM partial-sector RMW turned 8MB of writes into
// ~50us. Fix: thread = (pixel, 16 consecutive channels) so its 16 fp8
// bytes are ONE contiguous int4 store; half-wave stores = 2x256B dense.)
// 512 blocks x 512 thr: block = 32 px x 256 ch; px = tid&31, cu = tid>>5.
// b held in 16 regs across the sumsq reduce -> normalize+pack, no re-read.
__global__ __launch_bounds__(512) void prep_kernel(const float* __restrict__ a,
                                                   const float* __restrict__ b,
                                                   float* __restrict__ sumsq_a,
                                                   float* __restrict__ sumsq_b,
                                                   u8* __restrict__ aF, u8* __restrict__ bF,
                                                   u64* __restrict__ packed,
                                                   float* __restrict__ out) {
    __shared__ float red[16][33];
    __shared__ float invb_sh[32];
    const int tid = threadIdx.x;
    const int px = tid & 31, cu = tid >> 5;      // 16 channel-units x 32 pixels
    const int p0 = blockIdx.x * 32;
    const int p = p0 + px;
    const int c0 = cu * 16;
    const u32 g = (u32)(p >> 4), r = (u32)(p & 15);
    // unit cu covers channels cu*16..+15: kb=cu>>3, h=cu&1, q=(cu>>1)&3
    const u32 sbase = g * 4096u + (u32)(cu >> 3) * 2048u + (u32)(cu & 1) * 1024u
                    + ((u32)((cu >> 1) & 3) * 16u + r) * 16u;

    if (blockIdx.x < 32) packed[(size_t)blockIdx.x * 512 + tid] = 0ull;
    if (blockIdx.x == 0 && tid == 0) *out = 0.f;

    // ---- b: 16 channels of one pixel into regs + sumsq partial
    float bv[16];
    float s = 0.f;
    #pragma unroll
    for (int e = 0; e < 16; ++e) {
        bv[e] = b[(size_t)(c0 + e) * HW + p];
        s += bv[e] * bv[e];
    }
    red[cu][px] = s;
    __syncthreads();
    if (tid < 32) {
        float B = 0.f;
        #pragma unroll
        for (int j = 0; j < 16; ++j) B += red[j][tid];
        sumsq_b[p0 + tid] = B;
        invb_sh[tid] = 1.0f / (sqrtf(B + EPS) + EPS);
    }
    __syncthreads();

    // normalized b fragment: ONE dense int4 store
    {
        const float inv = invb_sh[px];
        int4 W;
        W.x = (int)pk4(bv[0] * inv, bv[1] * inv, bv[2] * inv, bv[3] * inv);
        W.y = (int)pk4(bv[4] * inv, bv[5] * inv, bv[6] * inv, bv[7] * inv);
        W.z = (int)pk4(bv[8] * inv, bv[9] * inv, bv[10] * inv, bv[11] * inv);
        W.w = (int)pk4(bv[12] * inv, bv[13] * inv, bv[14] * inv, bv[15] * inv);
        *(int4*)(bF + sbase) = W;
    }

    // ---- a: raw fragment (dense int4) + sumsq partial
    {
        float av[16];
        s = 0.f;
        #pragma unroll
        for (int e = 0; e < 16; ++e) {
            av[e] = a[(size_t)(c0 + e) * HW + p];
            s += av[e] * av[e];
        }
        int4 W;
        W.x = (int)pk4(av[0], av[1], av[2], av[3]);
        W.y = (int)pk4(av[4], av[5], av[6], av[7]);
        W.z = (int)pk4(av[8], av[9], av[10], av[11]);
        W.w = (int)pk4(av[12], av[13], av[14], av[15]);
        *(int4*)(aF + sbase) = W;
    }
    red[cu][px] = s;                 // safe: all reduce reads happened before sync2
    __syncthreads();
    if (tid < 32) {
        float A = 0.f;
        #pragma unroll
        for (int j = 0; j < 16; ++j) A += red[j][tid];
        sumsq_a[p0 + tid] = A;
    }
}

// ---------------------------------------------------------------------------
// G: fused GEMM + argmax, MX-scaled fp8 (unit scales) — VERBATIM the
// R8-verified kernel (78us, MfmaUtil 36%, WRITE 8192KB, 0 conflicts).
// R9 post-mortem: moving b-normalization into this loop cost +33us;
// normalization stays in prep. Simple 2-buffer __syncthreads schedule,
// wave tile 64x32, 3 blocks/CU, C = +64 bias -> positive acc, raw-bit pack.
__global__ __launch_bounds__(256, 3) void gemm_argmax(const u8* __restrict__ aF,
                                                      const u8* __restrict__ bF,
                                                      u64* __restrict__ packed) {
    __shared__ u8 sB[2][16384];
    const int tid = threadIdx.x;
    const int w = tid >> 6, lane = tid & 63;
    const int q4 = lane >> 4, r15 = lane & 15;
    const int wm = w >> 1, wn = w & 1;

    const u32 bid = blockIdx.x;
    const u32 ng = bid & 7;          // n-group -> XCD (L2-resident B panel)
    const u32 mt = bid >> 3;         // 0..127 M tile
    const int p0 = (int)mt * BM;

    // A fragments resident: slab g = mt*8 + wm*4 + mi; two 16B halves at
    // g*4096 + kb*2048 + {0,1024} + lane*16
    const u8* gA = aF + (((size_t)(mt * 8 + wm * 4)) << 12) + (u32)lane * 16;
    intx8 Afr[4][2];
    #pragma unroll
    for (int mi = 0; mi < 4; ++mi)
        #pragma unroll
        for (int kb = 0; kb < 2; ++kb)
            Afr[mi][kb] = __builtin_shufflevector(
                *(const intx4*)(gA + (u32)(mi * 4096 + kb * 2048)),
                *(const intx4*)(gA + (u32)(mi * 4096 + kb * 2048 + 1024)),
                0, 1, 2, 3, 4, 5, 6, 7);

    // B panel for this ng: qt slice = gQ + qt*16384, 16KB contiguous
    const u8* gQ = bF + ((size_t)ng << 19);
    const u32 so = (u32)w * 4096u + (u32)lane * 16u;    // stage src offset (per-lane)

    // prologue: stage qt=0 into buffer 0
    #pragma unroll
    for (int i = 0; i < 4; ++i)
        stage16(gQ + so + (u32)(i * 1024), &sB[0][w * 4096 + i * 1024]);

    float bestv[4][4];
    u32   bestq[4][4];
    #pragma unroll
    for (int mi = 0; mi < 4; ++mi)
        #pragma unroll
        for (int r = 0; r < 4; ++r) { bestv[mi][r] = -3.4e38f; bestq[mi][r] = 0; }

    u32 q0 = ng * 2048 + wn * 32 + (u32)r15;   // running col id (ni0); ni1 = +16
    const floatx4 C64 = {64.f, 64.f, 64.f, 64.f};
    const int SCL = 0x7F7F7F7F;      // E8M0 127 = 2^0 -> unit scale

    __syncthreads();                 // vmcnt(0) drain + barrier: buf0 ready

    int x = 0;
    for (int qt = 0; qt < 32; ++qt) {
        // stage qt+1 into the other buffer (loads span the whole compute phase)
        if (qt < 31) {
            const u8* gs = gQ + (u32)(qt + 1) * 16384u + so;
            u8* ls = &sB[x ^ 1][w * 4096];
            #pragma unroll
            for (int i = 0; i < 4; ++i)
                stage16(gs + (u32)(i * 1024), ls + i * 1024);
        }

        const u8* Lb = &sB[x][(u32)(wn * 2) * 4096u + (u32)lane * 16u];
        floatx4 acc[4][2];
        intx8 B0, B1;

        // kb = 0 (C = bias 64)
        { intx4 lo = *(const intx4*)(Lb);
          intx4 hi = *(const intx4*)(Lb + 1024);
          B0 = __builtin_shufflevector(lo, hi, 0, 1, 2, 3, 4, 5, 6, 7); }
        { intx4 lo = *(const intx4*)(Lb + 4096);
          intx4 hi = *(const intx4*)(Lb + 4096 + 1024);
          B1 = __builtin_shufflevector(lo, hi, 0, 1, 2, 3, 4, 5, 6, 7); }
        __builtin_amdgcn_s_setprio(1);
        #pragma unroll
        for (int mi = 0; mi < 4; ++mi)
            acc[mi][0] = __builtin_amdgcn_mfma_scale_f32_16x16x128_f8f6f4(
                Afr[mi][0], B0, C64, 0, 0, 0, SCL, 0, SCL);
        #pragma unroll
        for (int mi = 0; mi < 4; ++mi)
            acc[mi][1] = __builtin_amdgcn_mfma_scale_f32_16x16x128_f8f6f4(
                Afr[mi][0], B1, C64, 0, 0, 0, SCL, 0, SCL);
        __builtin_amdgcn_s_setprio(0);

        // kb = 1 (accumulate)
        { intx4 lo = *(const intx4*)(Lb + 2048);
          intx4 hi = *(const intx4*)(Lb + 2048 + 1024);
          B0 = __builtin_shufflevector(lo, hi, 0, 1, 2, 3, 4, 5, 6, 7); }
        { intx4 lo = *(const intx4*)(Lb + 4096 + 2048);
          intx4 hi = *(const intx4*)(Lb + 4096 + 2048 + 1024);
          B1 = __builtin_shufflevector(lo, hi, 0, 1, 2, 3, 4, 5, 6, 7); }
        __builtin_amdgcn_s_setprio(1);
        #pragma unroll
        for (int mi = 0; mi < 4; ++mi)
            acc[mi][0] = __builtin_amdgcn_mfma_scale_f32_16x16x128_f8f6f4(
                Afr[mi][1], B0, acc[mi][0], 0, 0, 0, SCL, 0, SCL);
        #pragma unroll
        for (int mi = 0; mi < 4; ++mi)
            acc[mi][1] = __builtin_amdgcn_mfma_scale_f32_16x16x128_f8f6f4(
                Afr[mi][1], B1, acc[mi][1], 0, 0, 0, SCL, 0, SCL);
        __builtin_amdgcn_s_setprio(0);

        // running argmax (ascending q scan, strict > keeps first = smallest q)
        #pragma unroll
        for (int mi = 0; mi < 4; ++mi)
            #pragma unroll
            for (int r = 0; r < 4; ++r) {
                float v = acc[mi][0][r];
                bool gt = v > bestv[mi][r];
                bestv[mi][r] = gt ? v : bestv[mi][r];
                bestq[mi][r] = gt ? q0 : bestq[mi][r];
            }
        #pragma unroll
        for (int mi = 0; mi < 4; ++mi)
            #pragma unroll
            for (int r = 0; r < 4; ++r) {
                float v = acc[mi][1][r];
                bool gt = v > bestv[mi][r];
                bestv[mi][r] = gt ? v : bestv[mi][r];
                bestq[mi][r] = gt ? (q0 + 16u) : bestq[mi][r];
            }
        q0 += 64u;

        __syncthreads();             // staged buffer landed; all reads of sB[x] done
        x ^= 1;
    }

    // final: pack (acc = s+64 > 0 -> float bits monotone as uint),
    // shuffle-reduce over r15 (stays in q4 group), 1 atomic/row/wave
    #pragma unroll
    for (int mi = 0; mi < 4; ++mi)
        #pragma unroll
        for (int r = 0; r < 4; ++r) {
            u64 pk = ((u64)__float_as_uint(bestv[mi][r]) << 32)
                   | (u64)(0xFFFFFFFFu - bestq[mi][r]);
            #pragma unroll
            for (int d = 1; d < 16; d <<= 1) {
                u64 o = __shfl_xor((unsigned long long)pk, d);
                pk = o > pk ? o : pk;
            }
            if (r15 == 0)
                atomicMax(&packed[p0 + wm * 64 + mi * 16 + q4 * 4 + r], pk);
        }
}

// ---------------------------------------------------------------------------
// L: loss from the argmax's own similarity value (no gather).
// Decode: hi = bits(s+64) -> s = asfloat(hi) - 64; lo = ~q.
__global__ void loss_kernel(const u64* __restrict__ packed,
                            const float* __restrict__ sumsq_a, const float* __restrict__ sumsq_b,
                            float* __restrict__ out) {
    int p = blockIdx.x * 256 + threadIdx.x;
    u64 pk = packed[p];
    float s = __uint_as_float((u32)(pk >> 32)) - 64.0f;
    u32 q = 0xFFFFFFFFu - (u32)(pk & 0xFFFFFFFFull);
    float A = sumsq_a[p], B = sumsq_b[q];
    float dot = s * (sqrtf(B + EPS) + EPS);
    float cossim = dot / ((sqrtf(A) + EPS) * (sqrtf(B) + EPS));
    float v = (1.0f - cossim) * (1.0f / (float)HW);
    #pragma unroll
    for (int d = 1; d < 64; d <<= 1) v += __shfl_xor(v, d);
    if ((threadIdx.x & 63) == 0) atomicAdd(out, v);
}

// ---------------------------------------------------------------------------
extern "C" void kernel_launch(void* const* d_in, const int* in_sizes, int n_in,
                              void* d_out, int out_size, void* d_ws, size_t ws_size,
                              hipStream_t stream) {
    const float* a = (const float*)d_in[0];
    const float* b = (const float*)d_in[1];
    float* out = (float*)d_out;
    char* ws = (char*)d_ws;

    u8*    aF      = (u8*)ws;                                    // 4 MB
    u8*    bF      = (u8*)(ws + (size_t)4 * 1024 * 1024);        // 4 MB
    float* sumsq_a = (float*)(ws + (size_t)8 * 1024 * 1024);     // 64 KB
    float* sumsq_b = sumsq_a + HW;
    u64*   packed  = (u64*)(sumsq_b + HW);                       // 128 KB

    prep_kernel<<<dim3(HW / 32), 512, 0, stream>>>(a, b, sumsq_a, sumsq_b, aF, bF, packed, out);
    gemm_argmax<<<dim3((HW / BM) * (HW / NG)), 256, 0, stream>>>(aF, bF, packed);
    loss_kernel<<<dim3(HW / 256), 256, 0, stream>>>(packed, sumsq_a, sumsq_b, out);
}